// Round 2
// 539.103 us; speedup vs baseline: 1.5443x; 1.5443x over previous
//
#include <hip/hip_runtime.h>
#include <hip/hip_bf16.h>

// CTC forward loss, T=4096, C=8192, L=512 -> S=1025 states.
//
// R7 == R6 resubmission (R6 bench died in the harness transport layer with no
// kernel-side diagnostics; source re-audited, no fault found):
//  Phase A (ctc_emit): per-row log2-softmax; emissions packed as dwords
//    (lo16 = blank/even state, hi16 = target/odd state), pair p stored at
//    row-dword index (p>>3) + 64*(p&7) so the scan's linear global_load_lds
//    staging yields bank-conflict-free ds_read_b32 (lane l reads dword
//    l + 64k -> bank l%32, 2-way aliasing = free). Row = exactly 2048 B
//    (state 1024 == blank == LO of lane 63's dword 7; no sideband needed).
//  Phase B (ctc_scan2b): TWO independent 1-wave blocks: block 0 computes
//    alpha forward over rows 0..2047, block 1 computes beta backward over
//    rows 4095..2048 via the exact mirror s~=1024-s (same code path,
//    mirrored dword indices + reversed allow flags). Staging is a 16-slot
//    LDS ring fed by global_load_lds (VGPR-free; R5's 64-VGPR register ring
//    was demoted to scratch: VGPR_Count=72 < ~110 live => ~380 cyc/step).
//    Counted s_waitcnt vmcnt(16) (never 0) keeps 8+ rows in flight; at step
//    t it guarantees rows <= t+4 landed and we read row t+2 (2 rows slack).
//    The scan loop contains no other vector-memory ops (LDS reads are
//    through address_space(3) pointers => ds_read, lgkmcnt only), so the
//    vmcnt ordering argument is exact. Pattern matches the HW-verified
//    m201 template (gload_lds + counted vmcnt + ds_read, no drain).
//  Phase C (ctc_combine): 1-wave exact log-domain cut:
//    Total = sum_s alpha_2047(s) * (b(s)+b(s+1)+allow(s+2)*b(s+2)),
//    b = beta_2048, with per-lane block-floating-point scales removed.

#define T_STEPS 4096
#define N_CLASSES 8192
#define ROWB 2048            // bytes per P row (512 dwords, pair-interleaved)
#define DG 12                // global->LDS prefetch distance (rows)
#define DEPTH 16             // LDS ring slots (32 KiB)
#define INV_LN2 1.4426950408889634f
#define LN2F 0.6931471805599453f

static __device__ __forceinline__ float wredMax(float v) {
#pragma unroll
  for (int d = 32; d >= 1; d >>= 1) v = fmaxf(v, __shfl_xor(v, d, 64));
  return v;
}
static __device__ __forceinline__ float wredSum(float v) {
#pragma unroll
  for (int d = 32; d >= 1; d >>= 1) v += __shfl_xor(v, d, 64);
  return v;
}

#define FEXP2(x) __builtin_amdgcn_exp2f(x)
#define FLOG2(x) __builtin_amdgcn_logf(x)

// ---------------- Phase A: emissions ----------------
__global__ __launch_bounds__(256) void ctc_emit(const float* __restrict__ logits,
                                                const int* __restrict__ targets,
                                                unsigned int* __restrict__ P,
                                                float* __restrict__ cvec) {
  __shared__ __align__(16) float row[N_CLASSES];
  __shared__ float red[4];
  const int t = blockIdx.x;
  const int tid = threadIdx.x;
  const int lane = tid & 63, wid = tid >> 6;
  const float4* src = (const float4*)(logits + (size_t)t * N_CLASSES);

  float4 v[8];
  float lmax = -3.0e38f;
#pragma unroll
  for (int k = 0; k < 8; ++k) {
    v[k] = src[tid + 256 * k];
    ((float4*)row)[tid + 256 * k] = v[k];
    lmax = fmaxf(lmax, fmaxf(fmaxf(v[k].x, v[k].y), fmaxf(v[k].z, v[k].w)));
  }
  lmax = wredMax(lmax);
  if (lane == 0) red[wid] = lmax;
  __syncthreads();
  const float rowmax = fmaxf(fmaxf(red[0], red[1]), fmaxf(red[2], red[3]));
  const float m2 = rowmax * INV_LN2;

  float acc = 0.f;
#pragma unroll
  for (int k = 0; k < 8; ++k) {
    acc += FEXP2(fmaf(v[k].x, INV_LN2, -m2));
    acc += FEXP2(fmaf(v[k].y, INV_LN2, -m2));
    acc += FEXP2(fmaf(v[k].z, INV_LN2, -m2));
    acc += FEXP2(fmaf(v[k].w, INV_LN2, -m2));
  }
  acc = wredSum(acc);
  __syncthreads();
  if (lane == 0) red[wid] = acc;
  __syncthreads();
  const float Z = red[0] + red[1] + red[2] + red[3];
  const float denom2 = m2 + FLOG2(Z);   // lp2[c] = x[c]/ln2 - denom2

  // 512 pairs: pair p = states (2p = blank, 2p+1 = targets[p])
  const float eb2 = fmaf(row[0], INV_LN2, -denom2);
  float et2[2];
  float gmax = eb2;
#pragma unroll
  for (int j = 0; j < 2; ++j) {
    const int p = tid + 256 * j;
    et2[j] = fmaf(row[targets[p]], INV_LN2, -denom2);
    gmax = fmaxf(gmax, et2[j]);
  }
  gmax = wredMax(gmax);
  __syncthreads();
  if (lane == 0) red[wid] = gmax;
  __syncthreads();
  const float ct = fmaxf(fmaxf(red[0], red[1]), fmaxf(red[2], red[3]));

  __hip_bfloat162* Prow = (__hip_bfloat162*)(P + (size_t)t * (ROWB / 4));
  __hip_bfloat162 pr;
  pr.x = __float2bfloat16(FEXP2(eb2 - ct));
#pragma unroll
  for (int j = 0; j < 2; ++j) {
    const int p = tid + 256 * j;
    pr.y = __float2bfloat16(FEXP2(et2[j] - ct));
    Prow[(p >> 3) | ((p & 7) << 6)] = pr;   // dword index = lane + 64*k
  }
  if (tid == 0) cvec[t] = ct;
}

// ---------------- Phase B: two 1-wave half-scans ----------------
#define UNPK_LO(u) __uint_as_float((u) << 16)
#define UNPK_HI(u) __uint_as_float((u) & 0xFFFF0000u)

template <int DIRN>
static __device__ __forceinline__ void scan_half(const unsigned char* __restrict__ Pb,
                                                 const int* __restrict__ targets,
                                                 unsigned char* lbuf,
                                                 float* __restrict__ rawOut,
                                                 int* __restrict__ omOut) {
  const int lane = threadIdx.x;

  // allow-skip flags for odd local states (global odd index kg = 8*lane+k)
  float al[8];
#pragma unroll
  for (int k = 0; k < 8; ++k) {
    const int kg = 8 * lane + k;
    if (DIRN == 0) {
      const int c = targets[kg];
      const int cm1 = (kg == 0) ? -1 : targets[kg - 1];
      al[k] = (c != 0 && c != cm1) ? 1.0f : 0.0f;
    } else {
      // mirrored state s~=2kg+1 <-> orig s=1023-2kg; skip source orig s+2:
      // allow iff kg>0 && targets[512-kg]!=0 && targets[512-kg]!=targets[511-kg]
      if (kg == 0) {
        al[k] = 0.0f;
      } else {
        const int c = targets[512 - kg];
        const int cm1 = targets[511 - kg];
        al[k] = (c != 0 && c != cm1) ? 1.0f : 0.0f;
      }
    }
  }

  // state registers; init from row 0 (fwd) / row 4095 mirrored (bwd)
  float a[16], b[16], a16 = 0.f, b16;
#pragma unroll
  for (int j = 0; j < 16; ++j) a[j] = 0.f;
  if (lane == 0) {
    const unsigned int pv0 = *(const unsigned int*)(
        Pb + (DIRN ? ((size_t)(T_STEPS - 1) * ROWB + 4 * 511) : (size_t)0));
    a[0] = __uint_as_float((pv0 & 0xFFFFu) << 16);
    a[1] = __uint_as_float(pv0 & 0xFFFF0000u);
  }
  int omega = 0;   // per-lane: stored = true * 2^omega
  int wprev = 0;
  int wd = 0;
  float Lraw = __shfl_up(a[15], 1, 64);

  // global staging pointer: row for step t is rowOf(t) = DIRN ? 4095-t : t
  const long long gstep = DIRN ? -(long long)ROWB : (long long)ROWB;
  const unsigned char* gp =
      Pb + (DIRN ? (size_t)(T_STEPS - 2) * ROWB : (size_t)ROWB) + 16 * lane;

#define STAGE_ROW(slot)                                                        \
  {                                                                            \
    unsigned char* lq = lbuf + (size_t)(slot) * ROWB;                          \
    __builtin_amdgcn_global_load_lds(                                          \
        (const __attribute__((address_space(1))) void*)gp,                     \
        (__attribute__((address_space(3))) void*)lq, 16, 0, 0);                \
    __builtin_amdgcn_global_load_lds(                                          \
        (const __attribute__((address_space(1))) void*)(gp + 1024),            \
        (__attribute__((address_space(3))) void*)(lq + 1024), 16, 0, 0);       \
    gp += gstep;                                                               \
  }

  // LDS -> reg: lane l's pair k sits at dword l+64k (fwd) or
  // (63-l)+64*(7-k) (bwd mirror). Bank = lane%32 either way: conflict-free.
  const int rl = DIRN ? (63 - lane) : lane;

#define LOADSLOT(slot, R0, R1, R2, R3, R4, R5, R6, R7)                         \
  {                                                                            \
    const __attribute__((address_space(3))) unsigned int* sp =                 \
        (const __attribute__((address_space(3))) unsigned int*)(               \
            lbuf + (size_t)(slot) * ROWB);                                     \
    R0 = sp[rl + (DIRN ? 448 : 0)];                                            \
    R1 = sp[rl + (DIRN ? 384 : 64)];                                           \
    R2 = sp[rl + (DIRN ? 320 : 128)];                                          \
    R3 = sp[rl + (DIRN ? 256 : 192)];                                          \
    R4 = sp[rl + (DIRN ? 192 : 256)];                                          \
    R5 = sp[rl + (DIRN ? 128 : 320)];                                          \
    R6 = sp[rl + (DIRN ? 64 : 384)];                                           \
    R7 = sp[rl + (DIRN ? 0 : 448)];                                            \
  }

  // prologue: stage rows for t=1..DG, then pre-read rows 1,2 into regs
#pragma unroll
  for (int tt = 1; tt <= DG; ++tt) STAGE_ROW(tt & 15);

  unsigned int p0, p1, p2, p3, p4, p5, p6, p7;   // odd-t rows
  unsigned int q0, q1, q2, q3, q4, q5, q6, q7;   // even-t rows
  asm volatile("s_waitcnt vmcnt(16)" ::: "memory");   // rows 1..4 landed
  LOADSLOT(1, p0, p1, p2, p3, p4, p5, p6, p7);
  LOADSLOT(2, q0, q1, q2, q3, q4, q5, q6, q7);

  int t = 1;

  // Per step: copy row-t regs to locals (renames away in SSA), issue DMA for
  // row t+DG, counted vmcnt (rows <= t+4 guaranteed landed; we need t+2),
  // ds_read row t+2 into the freed regs, then compute. No other vmem ops in
  // the loop body.
#define STEP_HEAD(R0, R1, R2, R3, R4, R5, R6, R7)                              \
    const unsigned int x0 = R0, x1 = R1, x2 = R2, x3 = R3, x4 = R4, x5 = R5,   \
                       x6 = R6, x7 = R7;                                       \
    STAGE_ROW((t + DG) & 15);                                                  \
    asm volatile("s_waitcnt vmcnt(16)" ::: "memory");                          \
    LOADSLOT((t + 2) & 15, R0, R1, R2, R3, R4, R5, R6, R7);

#define BODY_MID(A, B)                                                         \
    B[2] = (A[2] + A[1]) * UNPK_LO(x1);                                        \
    B[3] = fmaf(al[1], A[1], A[3] + A[2]) * UNPK_HI(x1);                       \
    B[4] = (A[4] + A[3]) * UNPK_LO(x2);                                        \
    B[5] = fmaf(al[2], A[3], A[5] + A[4]) * UNPK_HI(x2);                       \
    B[6] = (A[6] + A[5]) * UNPK_LO(x3);                                        \
    B[7] = fmaf(al[3], A[5], A[7] + A[6]) * UNPK_HI(x3);                       \
    B[8] = (A[8] + A[7]) * UNPK_LO(x4);                                        \
    B[9] = fmaf(al[4], A[7], A[9] + A[8]) * UNPK_HI(x4);                       \
    B[10] = (A[10] + A[9]) * UNPK_LO(x5);                                      \
    B[11] = fmaf(al[5], A[9], A[11] + A[10]) * UNPK_HI(x5);                    \
    B[12] = (A[12] + A[11]) * UNPK_LO(x6);                                     \
    B[13] = fmaf(al[6], A[11], A[13] + A[12]) * UNPK_HI(x6);                   \
    B[14] = (A[14] + A[13]) * UNPK_LO(x7);

#define STEPF(A, A16, B, B16, R0, R1, R2, R3, R4, R5, R6, R7)                  \
  {                                                                            \
    STEP_HEAD(R0, R1, R2, R3, R4, R5, R6, R7)                                  \
    B[15] = fmaf(al[7], A[13], A[15] + A[14]) * UNPK_HI(x7);                   \
    B16 = (lane == 63) ? (A16 + A[15]) * UNPK_LO(x7) : 0.f;                    \
    float newL = __shfl_up(B[15], 1, 64);                                      \
    float La = (lane == 0) ? 0.f : ldexpf(Lraw, wd);                           \
    B[0] = (A[0] + La) * UNPK_LO(x0);                                          \
    B[1] = fmaf(al[0], La, A[1] + A[0]) * UNPK_HI(x0);                         \
    BODY_MID(A, B)                                                             \
    Lraw = newL;                                                               \
    ++t;                                                                       \
  }

#define STEPS(A, A16, B, B16, R0, R1, R2, R3, R4, R5, R6, R7)                  \
  {                                                                            \
    STEP_HEAD(R0, R1, R2, R3, R4, R5, R6, R7)                                  \
    float La = (lane == 0) ? 0.f : ldexpf(Lraw, wd);                           \
    B[15] = fmaf(al[7], A[13], A[15] + A[14]) * UNPK_HI(x7);                   \
    B16 = (lane == 63) ? (A16 + A[15]) * UNPK_LO(x7) : 0.f;                    \
    B[0] = (A[0] + La) * UNPK_LO(x0);                                          \
    B[1] = fmaf(al[0], La, A[1] + A[0]) * UNPK_HI(x0);                         \
    BODY_MID(A, B)                                                             \
    float m = 0.f;                                                             \
    _Pragma("unroll") for (int j = 0; j < 16; ++j) m = fmaxf(m, B[j]);         \
    if (lane == 63) m = fmaxf(m, B16);                                         \
    if (m > 0.f) {                                                             \
      const int e = (int)((__float_as_uint(m) >> 23) & 255u);                  \
      const int shift = 127 - e;                                               \
      _Pragma("unroll") for (int j = 0; j < 16; ++j) B[j] = ldexpf(B[j], shift); \
      B16 = ldexpf(B16, shift);                                                \
      omega += shift;                                                          \
    } else {                                                                   \
      omega = wprev;                                                           \
    }                                                                          \
    wprev = __shfl_up(omega, 1, 64);                                           \
    wd = omega - wprev;                                                        \
    Lraw = __shfl_up(B[15], 1, 64);                                            \
    ++t;                                                                       \
  }

  for (int g = 0; g < 255; ++g) {   // steps t = 8g+1 .. 8g+8 (1..2040)
    STEPF(a, a16, b, b16, p0, p1, p2, p3, p4, p5, p6, p7);
    STEPF(b, b16, a, a16, q0, q1, q2, q3, q4, q5, q6, q7);
    STEPF(a, a16, b, b16, p0, p1, p2, p3, p4, p5, p6, p7);
    STEPF(b, b16, a, a16, q0, q1, q2, q3, q4, q5, q6, q7);
    STEPF(a, a16, b, b16, p0, p1, p2, p3, p4, p5, p6, p7);
    STEPF(b, b16, a, a16, q0, q1, q2, q3, q4, q5, q6, q7);
    STEPF(a, a16, b, b16, p0, p1, p2, p3, p4, p5, p6, p7);
    STEPS(b, b16, a, a16, q0, q1, q2, q3, q4, q5, q6, q7);   // rescale; ends in a
  }
  // steps t = 2041 .. 2047 (7 steps; result ends in b).
  // Staging reads rows up to rowOf(2059): fwd 2059 <= 4095, bwd 2036 >= 0.
  STEPF(a, a16, b, b16, p0, p1, p2, p3, p4, p5, p6, p7);
  STEPF(b, b16, a, a16, q0, q1, q2, q3, q4, q5, q6, q7);
  STEPF(a, a16, b, b16, p0, p1, p2, p3, p4, p5, p6, p7);
  STEPF(b, b16, a, a16, q0, q1, q2, q3, q4, q5, q6, q7);
  STEPF(a, a16, b, b16, p0, p1, p2, p3, p4, p5, p6, p7);
  STEPF(b, b16, a, a16, q0, q1, q2, q3, q4, q5, q6, q7);
  STEPF(a, a16, b, b16, p0, p1, p2, p3, p4, p5, p6, p7);

#pragma unroll
  for (int j = 0; j < 16; ++j) rawOut[16 * lane + j] = b[j];
  if (lane == 63) rawOut[1024] = b16;
  omOut[lane] = omega;

#undef STEPS
#undef STEPF
#undef BODY_MID
#undef STEP_HEAD
#undef LOADSLOT
#undef STAGE_ROW
}

__global__ __launch_bounds__(64, 1) void ctc_scan2b(const unsigned char* __restrict__ Pb,
                                                    const int* __restrict__ targets,
                                                    float* __restrict__ rawF,
                                                    int* __restrict__ omF,
                                                    float* __restrict__ rawB,
                                                    int* __restrict__ omB) {
  __shared__ __align__(16) unsigned char lbuf[DEPTH * ROWB];
  if (blockIdx.x == 0)
    scan_half<0>(Pb, targets, lbuf, rawF, omF);
  else
    scan_half<1>(Pb, targets, lbuf, rawB, omB);
}

// ---------------- Phase C: exact log-domain combine at the cut ----------------
__global__ __launch_bounds__(64) void ctc_combine(const float* __restrict__ cvec,
                                                  const int* __restrict__ targets,
                                                  const float* __restrict__ rawF,
                                                  const int* __restrict__ omF,
                                                  const float* __restrict__ rawB,
                                                  const int* __restrict__ omB,
                                                  float* __restrict__ out) {
  __shared__ float vb[1025];   // log2 beta_2048(s), orig state order
  const int lane = threadIdx.x;

  float sc = 0.f;
  for (int i = lane; i < T_STEPS; i += 64) sc += cvec[i];
  sc = wredSum(sc);

  // rawB is stored in mirrored order: index s~ -> orig state 1024 - s~
  const float wb = (float)omB[lane];
#pragma unroll
  for (int j = 0; j < 16; ++j) {
    const int st = 16 * lane + j;
    const float r = rawB[st];
    vb[1024 - st] = (r > 0.f) ? (FLOG2(r) - wb) : -1.0e30f;
  }
  if (lane == 63) {
    const float r = rawB[1024];   // mirrored state 1024 = orig state 0
    vb[0] = (r > 0.f) ? (FLOG2(r) - wb) : -1.0e30f;
  }
  __syncthreads();

  const float wf = (float)omF[lane];
  float vloc[16];
  float m = -3.0e38f;
#pragma unroll
  for (int j = 0; j < 16; ++j) {
    const int s = 16 * lane + j;
    const float af = rawF[s];
    const float vf = (af > 0.f) ? (FLOG2(af) - wf) : -1.0e30f;
    const float g1 = vb[s];
    const float g2 = vb[s + 1];
    float g3 = -1.0e30f;
    if (s & 1) {
      const int k = (s - 1) >> 1;
      if (k + 1 < 512) {
        const int c = targets[k + 1];
        if (c != 0 && c != targets[k]) g3 = vb[s + 2];
      }
    }
    const float gm = fmaxf(g1, fmaxf(g2, g3));
    float gl = -1.0e30f;
    if (gm > -1.0e29f)
      gl = gm + FLOG2(FEXP2(g1 - gm) + FEXP2(g2 - gm) + FEXP2(g3 - gm));
    const float vv = vf + gl;
    vloc[j] = vv;
    m = fmaxf(m, vv);
  }
  float v16 = -3.0e38f;
  if (lane == 63) {
    const float af = rawF[1024];
    const float vf = (af > 0.f) ? (FLOG2(af) - wf) : -1.0e30f;
    v16 = vf + vb[1024];   // state 1024 -> only self-transition
    m = fmaxf(m, v16);
  }
  m = wredMax(m);
  float ssum = 0.f;
#pragma unroll
  for (int j = 0; j < 16; ++j) ssum += FEXP2(vloc[j] - m);
  if (lane == 63) ssum += FEXP2(v16 - m);
  ssum = wredSum(ssum);
  if (lane == 0) out[0] = -LN2F * (m + FLOG2(ssum) + sc);
}

extern "C" void kernel_launch(void* const* d_in, const int* in_sizes, int n_in,
                              void* d_out, int out_size, void* d_ws, size_t ws_size,
                              hipStream_t stream) {
  (void)in_sizes; (void)n_in; (void)out_size; (void)ws_size;
  const float* logits = (const float*)d_in[0];
  const int* targets = (const int*)d_in[1];
  // ws layout: P dwords [4096 x 512] (8,388,608 B) | cvec f32[4096] |
  //            rawF f32[1025]+pad | omF i32[64] | rawB f32[1025]+pad | omB i32[64]
  char* ws = (char*)d_ws;
  unsigned int* P = (unsigned int*)ws;
  char* p = ws + (size_t)T_STEPS * ROWB;
  float* cvec = (float*)p;            p += T_STEPS * sizeof(float);
  float* rawF = (float*)p;            p += 1028 * sizeof(float);
  int* omF = (int*)p;                 p += 64 * sizeof(int);
  float* rawB = (float*)p;            p += 1028 * sizeof(float);
  int* omB = (int*)p;

  ctc_emit<<<dim3(T_STEPS), dim3(256), 0, stream>>>(logits, targets, P, cvec);
  ctc_scan2b<<<dim3(2), dim3(64), 0, stream>>>((const unsigned char*)P, targets,
                                               rawF, omF, rawB, omB);
  ctc_combine<<<dim3(1), dim3(64), 0, stream>>>(cvec, targets, rawF, omF, rawB, omB,
                                                (float*)d_out);
}

// Round 4
// 524.200 us; speedup vs baseline: 1.5882x; 1.0284x over previous
//
#include <hip/hip_runtime.h>
#include <hip/hip_bf16.h>

// CTC forward loss, T=4096, C=8192, L=512 -> S=1025 states.
//
// R9 == R8 with the compile fix: LDS 16B reads use a clang-native
// ext_vector_type (HIP's uint4 operator= cannot bind an AS(3) reference).
//
// R8 design (attacking the scan's 414 cyc/step stall; R6 post-mortem showed
// the per-step s_waitcnt vmcnt(16) binds on loads issued only 8 steps prior,
// implied single-wave gload_lds completion latency ~3.4k cyc):
//  - Grouped staging: stage 8 rows (16 loads) once per 8-step group into a
//    32-row (64 KiB) LDS ring; ONE s_waitcnt vmcnt(32) per group, waiting on
//    the batch issued 3 groups (24 steps) earlier. Peak 48 outstanding (<63).
//    Batches phase-shifted (+2 rows: batch g = rows 8g+3..8g+10) so the
//    group-top wait covers exactly the rows ds_read during that group.
//  - P-row layout permuted: pair p=8l+4b+c at dword 256b+4l+c, so each
//    lane's 8 pairs are two contiguous 16B chunks -> 2x ds_read_b128
//    (consecutive lanes read consecutive chunks: conflict-minimal) replacing
//    8x ds_read_b32. Backward mirror = lane 63-l's chunks, order swapped +
//    compile-time component reversal (reproduces R6's verified xk mapping).
//    global_load_lds stays linear (permutation at emit store + ds_read only).
//    Pair 511 -> dword 511 (init read unchanged).

#define T_STEPS 4096
#define N_CLASSES 8192
#define ROWB 2048            // bytes per P row (512 dwords, pair-permuted)
#define RMASK 65535          // 32-slot ring (64 KiB)
#define INV_LN2 1.4426950408889634f
#define LN2F 0.6931471805599453f

typedef unsigned int u32x4 __attribute__((ext_vector_type(4)));

static __device__ __forceinline__ float wredMax(float v) {
#pragma unroll
  for (int d = 32; d >= 1; d >>= 1) v = fmaxf(v, __shfl_xor(v, d, 64));
  return v;
}
static __device__ __forceinline__ float wredSum(float v) {
#pragma unroll
  for (int d = 32; d >= 1; d >>= 1) v += __shfl_xor(v, d, 64);
  return v;
}

#define FEXP2(x) __builtin_amdgcn_exp2f(x)
#define FLOG2(x) __builtin_amdgcn_logf(x)

// ---------------- Phase A: emissions ----------------
__global__ __launch_bounds__(256) void ctc_emit(const float* __restrict__ logits,
                                                const int* __restrict__ targets,
                                                unsigned int* __restrict__ P,
                                                float* __restrict__ cvec) {
  __shared__ __align__(16) float row[N_CLASSES];
  __shared__ float red[4];
  const int t = blockIdx.x;
  const int tid = threadIdx.x;
  const int lane = tid & 63, wid = tid >> 6;
  const float4* src = (const float4*)(logits + (size_t)t * N_CLASSES);

  float4 v[8];
  float lmax = -3.0e38f;
#pragma unroll
  for (int k = 0; k < 8; ++k) {
    v[k] = src[tid + 256 * k];
    ((float4*)row)[tid + 256 * k] = v[k];
    lmax = fmaxf(lmax, fmaxf(fmaxf(v[k].x, v[k].y), fmaxf(v[k].z, v[k].w)));
  }
  lmax = wredMax(lmax);
  if (lane == 0) red[wid] = lmax;
  __syncthreads();
  const float rowmax = fmaxf(fmaxf(red[0], red[1]), fmaxf(red[2], red[3]));
  const float m2 = rowmax * INV_LN2;

  float acc = 0.f;
#pragma unroll
  for (int k = 0; k < 8; ++k) {
    acc += FEXP2(fmaf(v[k].x, INV_LN2, -m2));
    acc += FEXP2(fmaf(v[k].y, INV_LN2, -m2));
    acc += FEXP2(fmaf(v[k].z, INV_LN2, -m2));
    acc += FEXP2(fmaf(v[k].w, INV_LN2, -m2));
  }
  acc = wredSum(acc);
  __syncthreads();
  if (lane == 0) red[wid] = acc;
  __syncthreads();
  const float Z = red[0] + red[1] + red[2] + red[3];
  const float denom2 = m2 + FLOG2(Z);   // lp2[c] = x[c]/ln2 - denom2

  // 512 pairs: pair p = states (2p = blank, 2p+1 = targets[p])
  const float eb2 = fmaf(row[0], INV_LN2, -denom2);
  float et2[2];
  float gmax = eb2;
#pragma unroll
  for (int j = 0; j < 2; ++j) {
    const int p = tid + 256 * j;
    et2[j] = fmaf(row[targets[p]], INV_LN2, -denom2);
    gmax = fmaxf(gmax, et2[j]);
  }
  gmax = wredMax(gmax);
  __syncthreads();
  if (lane == 0) red[wid] = gmax;
  __syncthreads();
  const float ct = fmaxf(fmaxf(red[0], red[1]), fmaxf(red[2], red[3]));

  __hip_bfloat162* Prow = (__hip_bfloat162*)(P + (size_t)t * (ROWB / 4));
  __hip_bfloat162 pr;
  pr.x = __float2bfloat16(FEXP2(eb2 - ct));
#pragma unroll
  for (int j = 0; j < 2; ++j) {
    const int p = tid + 256 * j;
    pr.y = __float2bfloat16(FEXP2(et2[j] - ct));
    // pair p -> dword ((p&4)<<6)|((p>>3)<<2)|(p&3): lane (p>>3) gets pairs
    // 8l..8l+3 at bytes 16l.., pairs 8l+4..8l+7 at 1024+16l..
    Prow[((p & 4) << 6) | ((p >> 3) << 2) | (p & 3)] = pr;
  }
  if (tid == 0) cvec[t] = ct;
}

// ---------------- Phase B: two 1-wave half-scans ----------------
#define UNPK_LO(u) __uint_as_float((u) << 16)
#define UNPK_HI(u) __uint_as_float((u) & 0xFFFF0000u)

template <int DIRN>
static __device__ __forceinline__ void scan_half(const unsigned char* __restrict__ Pb,
                                                 const int* __restrict__ targets,
                                                 unsigned char* lbuf,
                                                 float* __restrict__ rawOut,
                                                 int* __restrict__ omOut) {
  const int lane = threadIdx.x;

  // allow-skip flags for odd local states (global odd index kg = 8*lane+k)
  float al[8];
#pragma unroll
  for (int k = 0; k < 8; ++k) {
    const int kg = 8 * lane + k;
    if (DIRN == 0) {
      const int c = targets[kg];
      const int cm1 = (kg == 0) ? -1 : targets[kg - 1];
      al[k] = (c != 0 && c != cm1) ? 1.0f : 0.0f;
    } else {
      if (kg == 0) {
        al[k] = 0.0f;
      } else {
        const int c = targets[512 - kg];
        const int cm1 = targets[511 - kg];
        al[k] = (c != 0 && c != cm1) ? 1.0f : 0.0f;
      }
    }
  }

  // state registers; init from row 0 (fwd) / row 4095 mirrored (bwd)
  float a[16], b[16], a16 = 0.f, b16;
#pragma unroll
  for (int j = 0; j < 16; ++j) a[j] = 0.f;
  if (lane == 0) {
    // pair 0 -> dword 0; pair 511 -> dword 511 (permutation fixes both)
    const unsigned int pv0 = *(const unsigned int*)(
        Pb + (DIRN ? ((size_t)(T_STEPS - 1) * ROWB + 4 * 511) : (size_t)0));
    a[0] = __uint_as_float((pv0 & 0xFFFFu) << 16);
    a[1] = __uint_as_float(pv0 & 0xFFFF0000u);
  }
  int omega = 0;   // per-lane: stored = true * 2^omega
  int wprev = 0;
  int wd = 0;
  float Lraw = __shfl_up(a[15], 1, 64);

  // global staging pointer: row for step t is rowOf(t) = DIRN ? 4095-t : t
  const long long gstep = DIRN ? -(long long)ROWB : (long long)ROWB;
  const unsigned char* gp =
      Pb + (DIRN ? (size_t)(T_STEPS - 2) * ROWB : (size_t)ROWB) + 16 * lane;

#define STAGE_ROW(ldsByte)                                                     \
  {                                                                            \
    unsigned char* lq = lbuf + (ldsByte);                                      \
    __builtin_amdgcn_global_load_lds(                                          \
        (const __attribute__((address_space(1))) void*)gp,                     \
        (__attribute__((address_space(3))) void*)lq, 16, 0, 0);                \
    __builtin_amdgcn_global_load_lds(                                          \
        (const __attribute__((address_space(1))) void*)(gp + 1024),            \
        (__attribute__((address_space(3))) void*)(lq + 1024), 16, 0, 0);       \
    gp += gstep;                                                               \
  }

  // ds_read_b128 lane offsets: fwd lane l reads bytes [16l,16l+16) and
  // [1024+16l,..); bwd lane l reads lane (63-l)'s chunks, swapped order.
  const int o1 = DIRN ? (1024 + 16 * (63 - lane)) : (16 * lane);
  const int o2 = DIRN ? (16 * (63 - lane)) : (1024 + 16 * lane);

#define LOADSLOT(ldsByte, RA, RB)                                              \
  {                                                                            \
    RA = *(const __attribute__((address_space(3))) u32x4*)(lbuf + (ldsByte) + o1); \
    RB = *(const __attribute__((address_space(3))) u32x4*)(lbuf + (ldsByte) + o2); \
  }

  // prologue: stage rows 1,2 (slots 0,1) + batches 0..2 (rows 3..26,
  // slots 2..25); wait for rows 1,2 (52 issued, vmcnt(48)); preload regs.
  STAGE_ROW(0 * 2048)
  STAGE_ROW(1 * 2048)
#pragma unroll
  for (int r = 3; r <= 26; ++r) STAGE_ROW((r - 1) * 2048)
  asm volatile("s_waitcnt vmcnt(48)" ::: "memory");
  u32x4 pA, pB, qA, qB;   // rows t(odd) and t+1(even) prefetched in regs
  LOADSLOT(0 * 2048, pA, pB)   // row 1
  LOADSLOT(1 * 2048, qA, qB)   // row 2

  // Per step: unpack current row from regs (component order fixed by DIRN),
  // then ds_read row t+2 into the freed regs. No vmem, no waitcnt in steps.
#define STEP_HEAD(RA, RB, LDSB)                                                \
    unsigned int x0, x1, x2, x3, x4, x5, x6, x7;                               \
    if (DIRN == 0) {                                                           \
      x0 = RA.x; x1 = RA.y; x2 = RA.z; x3 = RA.w;                              \
      x4 = RB.x; x5 = RB.y; x6 = RB.z; x7 = RB.w;                              \
    } else {                                                                   \
      x0 = RA.w; x1 = RA.z; x2 = RA.y; x3 = RA.x;                              \
      x4 = RB.w; x5 = RB.z; x6 = RB.y; x7 = RB.x;                              \
    }                                                                          \
    LOADSLOT(LDSB, RA, RB)

#define BODY_MID(A, B)                                                         \
    B[2] = (A[2] + A[1]) * UNPK_LO(x1);                                        \
    B[3] = fmaf(al[1], A[1], A[3] + A[2]) * UNPK_HI(x1);                       \
    B[4] = (A[4] + A[3]) * UNPK_LO(x2);                                        \
    B[5] = fmaf(al[2], A[3], A[5] + A[4]) * UNPK_HI(x2);                       \
    B[6] = (A[6] + A[5]) * UNPK_LO(x3);                                        \
    B[7] = fmaf(al[3], A[5], A[7] + A[6]) * UNPK_HI(x3);                       \
    B[8] = (A[8] + A[7]) * UNPK_LO(x4);                                        \
    B[9] = fmaf(al[4], A[7], A[9] + A[8]) * UNPK_HI(x4);                       \
    B[10] = (A[10] + A[9]) * UNPK_LO(x5);                                      \
    B[11] = fmaf(al[5], A[9], A[11] + A[10]) * UNPK_HI(x5);                    \
    B[12] = (A[12] + A[11]) * UNPK_LO(x6);                                     \
    B[13] = fmaf(al[6], A[11], A[13] + A[12]) * UNPK_HI(x6);                   \
    B[14] = (A[14] + A[13]) * UNPK_LO(x7);

#define STEPF(A, A16, B, B16, RA, RB, LDSB)                                    \
  {                                                                            \
    STEP_HEAD(RA, RB, LDSB)                                                    \
    B[15] = fmaf(al[7], A[13], A[15] + A[14]) * UNPK_HI(x7);                   \
    B16 = (lane == 63) ? (A16 + A[15]) * UNPK_LO(x7) : 0.f;                    \
    float newL = __shfl_up(B[15], 1, 64);                                      \
    float La = (lane == 0) ? 0.f : ldexpf(Lraw, wd);                           \
    B[0] = (A[0] + La) * UNPK_LO(x0);                                          \
    B[1] = fmaf(al[0], La, A[1] + A[0]) * UNPK_HI(x0);                         \
    BODY_MID(A, B)                                                             \
    Lraw = newL;                                                               \
  }

#define STEPS(A, A16, B, B16, RA, RB, LDSB)                                    \
  {                                                                            \
    STEP_HEAD(RA, RB, LDSB)                                                    \
    float La = (lane == 0) ? 0.f : ldexpf(Lraw, wd);                           \
    B[15] = fmaf(al[7], A[13], A[15] + A[14]) * UNPK_HI(x7);                   \
    B16 = (lane == 63) ? (A16 + A[15]) * UNPK_LO(x7) : 0.f;                    \
    B[0] = (A[0] + La) * UNPK_LO(x0);                                          \
    B[1] = fmaf(al[0], La, A[1] + A[0]) * UNPK_HI(x0);                         \
    BODY_MID(A, B)                                                             \
    float m = 0.f;                                                             \
    _Pragma("unroll") for (int j = 0; j < 16; ++j) m = fmaxf(m, B[j]);         \
    if (lane == 63) m = fmaxf(m, B16);                                         \
    if (m > 0.f) {                                                             \
      const int e = (int)((__float_as_uint(m) >> 23) & 255u);                  \
      const int shift = 127 - e;                                               \
      _Pragma("unroll") for (int j = 0; j < 16; ++j) B[j] = ldexpf(B[j], shift); \
      B16 = ldexpf(B16, shift);                                                \
      omega += shift;                                                          \
    } else {                                                                   \
      omega = wprev;                                                           \
    }                                                                          \
    wprev = __shfl_up(omega, 1, 64);                                           \
    wd = omega - wprev;                                                        \
    Lraw = __shfl_up(B[15], 1, 64);                                            \
  }

  // Main loop: group g covers steps t=8g+1..8g+8. Group top: ONE counted
  // vmcnt(32) (retains batches g+1,g+2 => batch g = rows 8g+3..8g+10 landed,
  // issued 3 groups earlier), then stage batch g+3 (rows 8g+27..8g+34,
  // slots (row-1)&31). Steps j read row t+2 at slot byte (sbase+(2+j)*2048)
  // & RMASK, where sbase = (8g&31)*2048.
  int sbase = 0;
  for (int g = 0; g < 255; ++g) {
    asm volatile("s_waitcnt vmcnt(32)" ::: "memory");
    STAGE_ROW((sbase + 26 * 2048) & RMASK)
    STAGE_ROW((sbase + 27 * 2048) & RMASK)
    STAGE_ROW((sbase + 28 * 2048) & RMASK)
    STAGE_ROW((sbase + 29 * 2048) & RMASK)
    STAGE_ROW((sbase + 30 * 2048) & RMASK)
    STAGE_ROW((sbase + 31 * 2048) & RMASK)
    STAGE_ROW((sbase + 32 * 2048) & RMASK)
    STAGE_ROW((sbase + 33 * 2048) & RMASK)
    STEPF(a, a16, b, b16, pA, pB, (sbase + 2 * 2048) & RMASK);
    STEPF(b, b16, a, a16, qA, qB, (sbase + 3 * 2048) & RMASK);
    STEPF(a, a16, b, b16, pA, pB, (sbase + 4 * 2048) & RMASK);
    STEPF(b, b16, a, a16, qA, qB, (sbase + 5 * 2048) & RMASK);
    STEPF(a, a16, b, b16, pA, pB, (sbase + 6 * 2048) & RMASK);
    STEPF(b, b16, a, a16, qA, qB, (sbase + 7 * 2048) & RMASK);
    STEPF(a, a16, b, b16, pA, pB, (sbase + 8 * 2048) & RMASK);
    STEPS(b, b16, a, a16, qA, qB, (sbase + 9 * 2048) & RMASK);   // rescale
    sbase = (sbase + 16384) & RMASK;
  }
  // tail: steps t=2041..2047 (7 steps; result ends in b). Reads rows
  // 2043..2049 (batch 255, staged at g=252); one wait covers them.
  asm volatile("s_waitcnt vmcnt(32)" ::: "memory");
  STEPF(a, a16, b, b16, pA, pB, (sbase + 2 * 2048) & RMASK);
  STEPF(b, b16, a, a16, qA, qB, (sbase + 3 * 2048) & RMASK);
  STEPF(a, a16, b, b16, pA, pB, (sbase + 4 * 2048) & RMASK);
  STEPF(b, b16, a, a16, qA, qB, (sbase + 5 * 2048) & RMASK);
  STEPF(a, a16, b, b16, pA, pB, (sbase + 6 * 2048) & RMASK);
  STEPF(b, b16, a, a16, qA, qB, (sbase + 7 * 2048) & RMASK);
  STEPF(a, a16, b, b16, pA, pB, (sbase + 8 * 2048) & RMASK);

#pragma unroll
  for (int j = 0; j < 16; ++j) rawOut[16 * lane + j] = b[j];
  if (lane == 63) rawOut[1024] = b16;
  omOut[lane] = omega;

#undef STEPS
#undef STEPF
#undef BODY_MID
#undef STEP_HEAD
#undef LOADSLOT
#undef STAGE_ROW
}

__global__ __launch_bounds__(64, 1) void ctc_scan2b(const unsigned char* __restrict__ Pb,
                                                    const int* __restrict__ targets,
                                                    float* __restrict__ rawF,
                                                    int* __restrict__ omF,
                                                    float* __restrict__ rawB,
                                                    int* __restrict__ omB) {
  __shared__ __align__(16) unsigned char lbuf[32 * ROWB];   // 64 KiB ring
  if (blockIdx.x == 0)
    scan_half<0>(Pb, targets, lbuf, rawF, omF);
  else
    scan_half<1>(Pb, targets, lbuf, rawB, omB);
}

// ---------------- Phase C: exact log-domain combine at the cut ----------------
__global__ __launch_bounds__(64) void ctc_combine(const float* __restrict__ cvec,
                                                  const int* __restrict__ targets,
                                                  const float* __restrict__ rawF,
                                                  const int* __restrict__ omF,
                                                  const float* __restrict__ rawB,
                                                  const int* __restrict__ omB,
                                                  float* __restrict__ out) {
  __shared__ float vb[1025];   // log2 beta_2048(s), orig state order
  const int lane = threadIdx.x;

  float sc = 0.f;
  for (int i = lane; i < T_STEPS; i += 64) sc += cvec[i];
  sc = wredSum(sc);

  // rawB is stored in mirrored order: index s~ -> orig state 1024 - s~
  const float wb = (float)omB[lane];
#pragma unroll
  for (int j = 0; j < 16; ++j) {
    const int st = 16 * lane + j;
    const float r = rawB[st];
    vb[1024 - st] = (r > 0.f) ? (FLOG2(r) - wb) : -1.0e30f;
  }
  if (lane == 63) {
    const float r = rawB[1024];   // mirrored state 1024 = orig state 0
    vb[0] = (r > 0.f) ? (FLOG2(r) - wb) : -1.0e30f;
  }
  __syncthreads();

  const float wf = (float)omF[lane];
  float vloc[16];
  float m = -3.0e38f;
#pragma unroll
  for (int j = 0; j < 16; ++j) {
    const int s = 16 * lane + j;
    const float af = rawF[s];
    const float vf = (af > 0.f) ? (FLOG2(af) - wf) : -1.0e30f;
    const float g1 = vb[s];
    const float g2 = vb[s + 1];
    float g3 = -1.0e30f;
    if (s & 1) {
      const int k = (s - 1) >> 1;
      if (k + 1 < 512) {
        const int c = targets[k + 1];
        if (c != 0 && c != targets[k]) g3 = vb[s + 2];
      }
    }
    const float gm = fmaxf(g1, fmaxf(g2, g3));
    float gl = -1.0e30f;
    if (gm > -1.0e29f)
      gl = gm + FLOG2(FEXP2(g1 - gm) + FEXP2(g2 - gm) + FEXP2(g3 - gm));
    const float vv = vf + gl;
    vloc[j] = vv;
    m = fmaxf(m, vv);
  }
  float v16 = -3.0e38f;
  if (lane == 63) {
    const float af = rawF[1024];
    const float vf = (af > 0.f) ? (FLOG2(af) - wf) : -1.0e30f;
    v16 = vf + vb[1024];   // state 1024 -> only self-transition
    m = fmaxf(m, v16);
  }
  m = wredMax(m);
  float ssum = 0.f;
#pragma unroll
  for (int j = 0; j < 16; ++j) ssum += FEXP2(vloc[j] - m);
  if (lane == 63) ssum += FEXP2(v16 - m);
  ssum = wredSum(ssum);
  if (lane == 0) out[0] = -LN2F * (m + FLOG2(ssum) + sc);
}

extern "C" void kernel_launch(void* const* d_in, const int* in_sizes, int n_in,
                              void* d_out, int out_size, void* d_ws, size_t ws_size,
                              hipStream_t stream) {
  (void)in_sizes; (void)n_in; (void)out_size; (void)ws_size;
  const float* logits = (const float*)d_in[0];
  const int* targets = (const int*)d_in[1];
  // ws layout: P dwords [4096 x 512] (8,388,608 B) | cvec f32[4096] |
  //            rawF f32[1025]+pad | omF i32[64] | rawB f32[1025]+pad | omB i32[64]
  char* ws = (char*)d_ws;
  unsigned int* P = (unsigned int*)ws;
  char* p = ws + (size_t)T_STEPS * ROWB;
  float* cvec = (float*)p;            p += T_STEPS * sizeof(float);
  float* rawF = (float*)p;            p += 1028 * sizeof(float);
  int* omF = (int*)p;                 p += 64 * sizeof(int);
  float* rawB = (float*)p;            p += 1028 * sizeof(float);
  int* omB = (int*)p;

  ctc_emit<<<dim3(T_STEPS), dim3(256), 0, stream>>>(logits, targets, P, cvec);
  ctc_scan2b<<<dim3(2), dim3(64), 0, stream>>>((const unsigned char*)P, targets,
                                               rawF, omF, rawB, omB);
  ctc_combine<<<dim3(1), dim3(64), 0, stream>>>(cvec, targets, rawF, omF, rawB, omB,
                                                (float*)d_out);
}

// Round 6
// 518.168 us; speedup vs baseline: 1.6067x; 1.0116x over previous
//
#include <hip/hip_runtime.h>
#include <hip/hip_bf16.h>

// CTC forward loss, T=4096, C=8192, L=512 -> S=1025 states.
//
// R11 == R10 + wave-boundary relay fixes (R10 NaN post-mortem):
//  (1) relay scale conversion had the SIGN inverted: reader must rescale the
//      upstream raw by 2^(omega_self - omega_up) (matching the intra-wave
//      wd = omega - wprev path). The inverted sign overflowed to inf at the
//      reachability frontier (omega_up >> omega_self), and inf * 0-emission
//      (bf16 underflow) = NaN.
//  (2) omega inheritance across the boundary: tid64's shfl_up wprev is its
//      OWN omega (no cross-wave shuffle), so wave1's frontier lane never
//      aligned frames. Fix: at rescale steps tid64 takes wprev from the
//      relayed omega (pay.y).
//
// R10 design (scan is single-wave ISSUE-bound; R9 grouped staging only moved
// 414->395 cyc/step):
//  - P layout: even states share the blank emission -> per row 512 odd bf16
//    (dword d: lo=pair 2d odd, hi=pair 2d+1 odd) + f32 pb[t]. Row = 1024 B.
//  - Phase B: per half-scan ONE block of 128 threads (2 waves), 8 states
//    (4 pairs) per thread. Intra-wave boundary via __shfl_up; the single
//    wave0->wave1 boundary {raw, omega} via a 4-slot LDS relay ring written
//    by tid63 each step, read next step. Lockstep via raw s_barrier
//    (+ lgkmcnt(0); no vmcnt drain, so the global_load_lds pipeline lives).
//  - Staging: 64-row (64 KiB) LDS ring, each wave stages 4 rows/group,
//    vmcnt(4) at group top (3-group slack); pb staged in 64-entry chunks
//    (256 B, double-buffered), reversed global source for backward block.
//  - Backward mirror s~=1024-s (R6-verified): thread T reads dwords
//    254-2T,255-2T with compile-time component reversal; allow kg=4T+k.

#define T_STEPS 4096
#define N_CLASSES 8192
#define ROWB 1024
#define INV_LN2 1.4426950408889634f
#define LN2F 0.6931471805599453f

typedef unsigned int u32x2 __attribute__((ext_vector_type(2)));

static __device__ __forceinline__ float wredMax(float v) {
#pragma unroll
  for (int d = 32; d >= 1; d >>= 1) v = fmaxf(v, __shfl_xor(v, d, 64));
  return v;
}
static __device__ __forceinline__ float wredSum(float v) {
#pragma unroll
  for (int d = 32; d >= 1; d >>= 1) v += __shfl_xor(v, d, 64);
  return v;
}

#define FEXP2(x) __builtin_amdgcn_exp2f(x)
#define FLOG2(x) __builtin_amdgcn_logf(x)
#define UNPK_LO(u) __uint_as_float((u) << 16)
#define UNPK_HI(u) __uint_as_float((u) & 0xFFFF0000u)

// ---------------- Phase A: emissions ----------------
__global__ __launch_bounds__(256) void ctc_emit(const float* __restrict__ logits,
                                                const int* __restrict__ targets,
                                                unsigned int* __restrict__ P,
                                                float* __restrict__ pbArr,
                                                float* __restrict__ cvec) {
  __shared__ __align__(16) float row[N_CLASSES];
  __shared__ float red[4];
  const int t = blockIdx.x;
  const int tid = threadIdx.x;
  const int lane = tid & 63, wid = tid >> 6;
  const float4* src = (const float4*)(logits + (size_t)t * N_CLASSES);

  float4 v[8];
  float lmax = -3.0e38f;
#pragma unroll
  for (int k = 0; k < 8; ++k) {
    v[k] = src[tid + 256 * k];
    ((float4*)row)[tid + 256 * k] = v[k];
    lmax = fmaxf(lmax, fmaxf(fmaxf(v[k].x, v[k].y), fmaxf(v[k].z, v[k].w)));
  }
  lmax = wredMax(lmax);
  if (lane == 0) red[wid] = lmax;
  __syncthreads();
  const float rowmax = fmaxf(fmaxf(red[0], red[1]), fmaxf(red[2], red[3]));
  const float m2 = rowmax * INV_LN2;

  float acc = 0.f;
#pragma unroll
  for (int k = 0; k < 8; ++k) {
    acc += FEXP2(fmaf(v[k].x, INV_LN2, -m2));
    acc += FEXP2(fmaf(v[k].y, INV_LN2, -m2));
    acc += FEXP2(fmaf(v[k].z, INV_LN2, -m2));
    acc += FEXP2(fmaf(v[k].w, INV_LN2, -m2));
  }
  acc = wredSum(acc);
  __syncthreads();
  if (lane == 0) red[wid] = acc;
  __syncthreads();
  const float Z = red[0] + red[1] + red[2] + red[3];
  const float denom2 = m2 + FLOG2(Z);   // lp2[c] = x[c]/ln2 - denom2

  const float eb2 = fmaf(row[0], INV_LN2, -denom2);
  const float e0 = fmaf(row[targets[2 * tid]], INV_LN2, -denom2);
  const float e1 = fmaf(row[targets[2 * tid + 1]], INV_LN2, -denom2);
  float gmax = fmaxf(eb2, fmaxf(e0, e1));
  gmax = wredMax(gmax);
  __syncthreads();
  if (lane == 0) red[wid] = gmax;
  __syncthreads();
  const float ct = fmaxf(fmaxf(red[0], red[1]), fmaxf(red[2], red[3]));

  __hip_bfloat162 pr;
  pr.x = __float2bfloat16(FEXP2(e0 - ct));   // odd of pair 2*tid
  pr.y = __float2bfloat16(FEXP2(e1 - ct));   // odd of pair 2*tid+1
  ((__hip_bfloat162*)(P + (size_t)t * (ROWB / 4)))[tid] = pr;
  if (tid == 0) {
    cvec[t] = ct;
    pbArr[t] = FEXP2(eb2 - ct);              // blank emission, f32
  }
}

// ---------------- Phase B: two-wave half-scan ----------------
// LDS map: [0,65536) row ring (64 slots x 1024B) | [65536,66048) pb (2x256B)
//          | [66048,66080) relay (4 slots x 8B)
#define PBB 65536
#define RLB 66048

template <int DIRN>
static __device__ __forceinline__ void scan_half(const unsigned char* __restrict__ Pb,
                                                 const float* __restrict__ pbArr,
                                                 const int* __restrict__ targets,
                                                 unsigned char* lbuf,
                                                 float* __restrict__ rawOut,
                                                 int* __restrict__ omOut) {
  const int tid = threadIdx.x;           // 0..127
  const int lane = tid & 63;
  const int w = tid >> 6;
  const bool isTop = (tid == 127);
  const int rowoff = DIRN ? (1016 - 8 * tid) : (8 * tid);

  // allow-skip flags, odd state 8T+2k+1 -> kg = 4T+k
  float al[4];
#pragma unroll
  for (int k = 0; k < 4; ++k) {
    const int kg = 4 * tid + k;
    if (DIRN == 0) {
      const int c = targets[kg];
      const int cm1 = (kg == 0) ? -1 : targets[kg - 1];
      al[k] = (c != 0 && c != cm1) ? 1.0f : 0.0f;
    } else {
      if (kg == 0) al[k] = 0.0f;
      else {
        const int c = targets[512 - kg];
        al[k] = (c != 0 && c != targets[511 - kg]) ? 1.0f : 0.0f;
      }
    }
  }

  // init state (row 0 fwd / row 4095 mirrored bwd)
  float a[8], b[8], a16 = 0.f, b16;
#pragma unroll
  for (int j = 0; j < 8; ++j) a[j] = 0.f;
  if (tid == 0) {
    if (DIRN == 0) {
      const unsigned int d0 = *(const unsigned int*)(Pb);
      a[0] = pbArr[0];
      a[1] = UNPK_LO(d0);
    } else {
      const unsigned int d = *(const unsigned int*)(Pb + (size_t)4095 * ROWB + 4 * 255);
      a[0] = pbArr[4095];
      a[1] = UNPK_HI(d);
    }
  }
  int omega = 0, wprev = 0, wd = 0;
  float Lraw = __shfl_up(a[7], 1, 64);   // all zeros

#define STAGE_STEP(rr)                                                         \
  { const int r_ = (rr);                                                       \
    const unsigned char* gs_ = Pb + ((size_t)(DIRN ? (4095 - r_) : r_) << 10) + 16 * lane; \
    __builtin_amdgcn_global_load_lds(                                          \
        (const __attribute__((address_space(1))) void*)gs_,                    \
        (__attribute__((address_space(3))) void*)(lbuf + ((r_ & 63) << 10)),   \
        16, 0, 0); }

#define STAGE_PB(cc)                                                           \
  { const int c_ = (cc);                                                       \
    const float* ps_ = pbArr + (DIRN ? (4094 - 64 * c_ - lane) : (64 * c_ + 1 + lane)); \
    __builtin_amdgcn_global_load_lds(                                          \
        (const __attribute__((address_space(1))) void*)ps_,                    \
        (__attribute__((address_space(3))) void*)(lbuf + PBB + ((c_ & 1) << 8)), \
        4, 0, 0); }

  // prologue: stage rows 1..32 (wave w: 8k+1+4w..+3) + pb chunk0
#pragma unroll
  for (int k = 0; k < 4; ++k) {
    const int rb = 8 * k + 1 + 4 * w;
    STAGE_STEP(rb) STAGE_STEP(rb + 1) STAGE_STEP(rb + 2) STAGE_STEP(rb + 3)
  }
  if (w == 0) STAGE_PB(0)
  asm volatile("s_waitcnt vmcnt(0)" ::: "memory");
  // zero relay ring (wave1 lanes 0..3)
  if (tid >= 64 && tid < 68) {
    u32x2 z; z.x = 0u; z.y = 0u;
    *(__attribute__((address_space(3))) u32x2*)(lbuf + RLB + ((tid - 64) << 3)) = z;
  }
  asm volatile("s_waitcnt lgkmcnt(0)" ::: "memory");
  __builtin_amdgcn_s_barrier();
  asm volatile("" ::: "memory");

  // prime register pipeline (rows 1,2 / pb words 0,1)
  u32x2 dP = *(const __attribute__((address_space(3))) u32x2*)(lbuf + 1024 + rowoff);
  u32x2 dQ = *(const __attribute__((address_space(3))) u32x2*)(lbuf + 2048 + rowoff);
  float pbP = *(const __attribute__((address_space(3))) float*)(lbuf + PBB + 0);
  float pbQ = *(const __attribute__((address_space(3))) float*)(lbuf + PBB + 4);

#define ENDBAR                                                                 \
    asm volatile("s_waitcnt lgkmcnt(0)" ::: "memory");                         \
    __builtin_amdgcn_s_barrier();                                              \
    asm volatile("" ::: "memory");

  // Per step: consume row regs; refill for t+2; relay read (slot (j-1)&3,
  // written last step); compute top states first -> relay write + shfl
  // early; then rest. Relay frame conversion: stored = true*2^omega, so
  // reader scales raw_up by 2^(omega_self - omega_up)  [R11 fix].
#define STEP_TOP(A, A16, B, B16, D01, PBR, JJ)                                 \
    const unsigned int x0 = D01.x, x1 = D01.y;                                 \
    const float pbc = PBR;                                                     \
    D01 = *(const __attribute__((address_space(3))) u32x2*)(                   \
        lbuf + ((sb + ((JJ) + 2) * 1024) & 65535) + rowoff);                   \
    PBR = *(const __attribute__((address_space(3))) float*)(                   \
        lbuf + PBB + (((t0 + (JJ) + 1) & 127) << 2));                          \
    const u32x2 pay = *(const __attribute__((address_space(3))) u32x2*)(       \
        lbuf + RLB + ((((JJ)-1) & 3) << 3));                                   \
    const float H3 = DIRN ? UNPK_LO(x0) : UNPK_HI(x1);                         \
    B[7] = fmaf(al[3], A[5], A[7] + A[6]) * H3;                                \
    if (tid == 63) {                                                           \
      u32x2 wv; wv.x = __float_as_uint(B[7]); wv.y = (unsigned)omega;          \
      *(__attribute__((address_space(3))) u32x2*)(lbuf + RLB + (((JJ)&3) << 3)) = wv; \
    }                                                                          \
    float newL = __shfl_up(B[7], 1, 64);                                       \
    const float H0 = DIRN ? UNPK_HI(x1) : UNPK_LO(x0);                         \
    const float H1 = DIRN ? UNPK_LO(x1) : UNPK_HI(x0);                         \
    const float H2 = DIRN ? UNPK_HI(x0) : UNPK_LO(x1);                         \
    B[4] = (A[4] + A[3]) * pbc;                                                \
    B[5] = fmaf(al[2], A[3], A[5] + A[4]) * H2;                                \
    B[6] = (A[6] + A[5]) * pbc;                                                \
    B16 = isTop ? (A16 + A[7]) * pbc : 0.f;                                    \
    const float Lsc = ldexpf(Lraw, wd);                                        \
    const float Lre = ldexpf(__uint_as_float(pay.x), omega - (int)pay.y);      \
    const float La = (lane != 0) ? Lsc : ((tid == 0) ? 0.f : Lre);             \
    B[0] = (A[0] + La) * pbc;                                                  \
    B[1] = fmaf(al[0], La, A[1] + A[0]) * H0;                                  \
    B[2] = (A[2] + A[1]) * pbc;                                                \
    B[3] = fmaf(al[1], A[1], A[3] + A[2]) * H1;

#define STEPF(A, A16, B, B16, D01, PBR, JJ)                                    \
  { STEP_TOP(A, A16, B, B16, D01, PBR, JJ)                                     \
    Lraw = newL;                                                               \
    ENDBAR }

#define STEPS(A, A16, B, B16, D01, PBR, JJ)                                    \
  { STEP_TOP(A, A16, B, B16, D01, PBR, JJ)                                     \
    (void)newL;                                                                \
    if (tid == 64) wprev = (int)pay.y;  /* R11: inherit frame across waves */  \
    float m = 0.f;                                                             \
    _Pragma("unroll") for (int j = 0; j < 8; ++j) m = fmaxf(m, B[j]);          \
    if (isTop) m = fmaxf(m, B16);                                              \
    if (m > 0.f) {                                                             \
      const int e = (int)((__float_as_uint(m) >> 23) & 255u);                  \
      const int sh = 127 - e;                                                  \
      _Pragma("unroll") for (int j = 0; j < 8; ++j) B[j] = ldexpf(B[j], sh);   \
      B16 = ldexpf(B16, sh);                                                   \
      omega += sh;                                                             \
    } else omega = wprev;                                                      \
    wprev = __shfl_up(omega, 1, 64);                                           \
    wd = omega - wprev;                                                        \
    Lraw = __shfl_up(B[7], 1, 64);                                             \
    ENDBAR }

  int t0 = 0, sb = 0;
  for (int G = 0; G < 255; ++G) {   // steps t = t0+1 .. t0+8
    asm volatile("s_waitcnt vmcnt(4)" ::: "memory");
    { const int rb = t0 + 33 + 4 * w;   // stage group G+4
      STAGE_STEP(rb) STAGE_STEP(rb + 1) STAGE_STEP(rb + 2) STAGE_STEP(rb + 3) }
    if (w == 0 && (G & 7) == 0) STAGE_PB((G >> 3) + 1)
    STEPF(a, a16, b, b16, dP, pbP, 1)
    STEPF(b, b16, a, a16, dQ, pbQ, 2)
    STEPF(a, a16, b, b16, dP, pbP, 3)
    STEPF(b, b16, a, a16, dQ, pbQ, 4)
    STEPF(a, a16, b, b16, dP, pbP, 5)
    STEPF(b, b16, a, a16, dQ, pbQ, 6)
    STEPF(a, a16, b, b16, dP, pbP, 7)
    STEPS(b, b16, a, a16, dQ, pbQ, 8)   // rescale; ends in a
    t0 += 8;
    sb = (sb + 8192) & 65535;
  }
  // tail: t = 2041..2047 (7 steps; result in b). Refills read rows <= 2049
  // (staged at groups <= 252, guaranteed by the wait below).
  asm volatile("s_waitcnt vmcnt(4)" ::: "memory");
  STEPF(a, a16, b, b16, dP, pbP, 1)
  STEPF(b, b16, a, a16, dQ, pbQ, 2)
  STEPF(a, a16, b, b16, dP, pbP, 3)
  STEPF(b, b16, a, a16, dQ, pbQ, 4)
  STEPF(a, a16, b, b16, dP, pbP, 5)
  STEPF(b, b16, a, a16, dQ, pbQ, 6)
  STEPF(a, a16, b, b16, dP, pbP, 7)

#pragma unroll
  for (int j = 0; j < 8; ++j) rawOut[8 * tid + j] = b[j];
  if (tid == 127) rawOut[1024] = b16;
  omOut[tid] = omega;

#undef STEPS
#undef STEPF
#undef STEP_TOP
#undef ENDBAR
#undef STAGE_PB
#undef STAGE_STEP
}

__global__ __launch_bounds__(128, 1) void ctc_scan2w(const unsigned char* __restrict__ Pb,
                                                     const float* __restrict__ pbArr,
                                                     const int* __restrict__ targets,
                                                     float* __restrict__ rawF,
                                                     int* __restrict__ omF,
                                                     float* __restrict__ rawB,
                                                     int* __restrict__ omB) {
  __shared__ __align__(16) unsigned char lbuf[66112];
  if (blockIdx.x == 0)
    scan_half<0>(Pb, pbArr, targets, lbuf, rawF, omF);
  else
    scan_half<1>(Pb, pbArr, targets, lbuf, rawB, omB);
}

// ---------------- Phase C: exact log-domain combine at the cut ----------------
__global__ __launch_bounds__(64) void ctc_combine(const float* __restrict__ cvec,
                                                  const int* __restrict__ targets,
                                                  const float* __restrict__ rawF,
                                                  const int* __restrict__ omF,
                                                  const float* __restrict__ rawB,
                                                  const int* __restrict__ omB,
                                                  float* __restrict__ out) {
  __shared__ float vb[1025];   // log2 beta_2048(s), orig state order
  const int lane = threadIdx.x;

  float sc = 0.f;
  for (int i = lane; i < T_STEPS; i += 64) sc += cvec[i];
  sc = wredSum(sc);

  // rawB is in mirrored order: index s~ -> orig state 1024 - s~; omega
  // arrays are per-scan-thread (128 entries, 8 states each).
  const float wb0 = (float)omB[2 * lane];
  const float wb1 = (float)omB[2 * lane + 1];
#pragma unroll
  for (int j = 0; j < 16; ++j) {
    const int st = 16 * lane + j;
    const float r = rawB[st];
    const float wb = (j < 8) ? wb0 : wb1;
    vb[1024 - st] = (r > 0.f) ? (FLOG2(r) - wb) : -1.0e30f;
  }
  if (lane == 63) {
    const float r = rawB[1024];   // mirrored state 1024 = orig state 0
    vb[0] = (r > 0.f) ? (FLOG2(r) - (float)omB[127]) : -1.0e30f;
  }
  __syncthreads();

  const float wf0 = (float)omF[2 * lane];
  const float wf1 = (float)omF[2 * lane + 1];
  float vloc[16];
  float m = -3.0e38f;
#pragma unroll
  for (int j = 0; j < 16; ++j) {
    const int s = 16 * lane + j;
    const float af = rawF[s];
    const float wf = (j < 8) ? wf0 : wf1;
    const float vf = (af > 0.f) ? (FLOG2(af) - wf) : -1.0e30f;
    const float g1 = vb[s];
    const float g2 = vb[s + 1];
    float g3 = -1.0e30f;
    if (s & 1) {
      const int k = (s - 1) >> 1;
      if (k + 1 < 512) {
        const int c = targets[k + 1];
        if (c != 0 && c != targets[k]) g3 = vb[s + 2];
      }
    }
    const float gm = fmaxf(g1, fmaxf(g2, g3));
    float gl = -1.0e30f;
    if (gm > -1.0e29f)
      gl = gm + FLOG2(FEXP2(g1 - gm) + FEXP2(g2 - gm) + FEXP2(g3 - gm));
    const float vv = vf + gl;
    vloc[j] = vv;
    m = fmaxf(m, vv);
  }
  float v16 = -3.0e38f;
  if (lane == 63) {
    const float af = rawF[1024];
    const float vf = (af > 0.f) ? (FLOG2(af) - (float)omF[127]) : -1.0e30f;
    v16 = vf + vb[1024];   // state 1024 -> only self-transition
    m = fmaxf(m, v16);
  }
  m = wredMax(m);
  float ssum = 0.f;
#pragma unroll
  for (int j = 0; j < 16; ++j) ssum += FEXP2(vloc[j] - m);
  if (lane == 63) ssum += FEXP2(v16 - m);
  ssum = wredSum(ssum);
  if (lane == 0) out[0] = -LN2F * (m + FLOG2(ssum) + sc);
}

extern "C" void kernel_launch(void* const* d_in, const int* in_sizes, int n_in,
                              void* d_out, int out_size, void* d_ws, size_t ws_size,
                              hipStream_t stream) {
  (void)in_sizes; (void)n_in; (void)out_size; (void)ws_size;
  const float* logits = (const float*)d_in[0];
  const int* targets = (const int*)d_in[1];
  // ws: P u32[4096 x 256] (4 MiB) | pbArr f32[4096] | cvec f32[4096] |
  //     rawF f32[1028] | omF i32[128] | rawB f32[1028] | omB i32[128]
  char* ws = (char*)d_ws;
  unsigned int* P = (unsigned int*)ws;
  float* pbArr = (float*)(ws + (size_t)T_STEPS * ROWB);
  float* cvec = pbArr + T_STEPS;
  float* rawF = cvec + T_STEPS;
  int* omF = (int*)(rawF + 1028);
  float* rawB = (float*)(omF + 128);
  int* omB = (int*)(rawB + 1028);

  ctc_emit<<<dim3(T_STEPS), dim3(256), 0, stream>>>(logits, targets, P, pbArr, cvec);
  ctc_scan2w<<<dim3(2), dim3(128), 0, stream>>>((const unsigned char*)P, pbArr,
                                                targets, rawF, omF, rawB, omB);
  ctc_combine<<<dim3(1), dim3(64), 0, stream>>>(cvec, targets, rawF, omF, rawB, omB,
                                                (float*)d_out);
}